// Round 6
// baseline (337.691 us; speedup 1.0000x reference)
//
#include <hip/hip_runtime.h>
#include <hip/hip_bf16.h>
#include <math.h>

#define N_TOK 16384
#define D_MODEL 2048
#define N_EXP 64
#define CAPACITY 640
#define KSPLIT 4
#define KSLICE (D_MODEL / KSPLIT)  // 512
#define NREP 8

// ---------------- K0: transpose W[e][k] -> Wt[k][e] -------------------------
// 32768 float4 reads (coalesced along k); scattered 4B writes absorbed by L2.
__global__ __launch_bounds__(256) void k0_transpose(
    const float* __restrict__ W, float* __restrict__ Wt) {
  const int tid = blockIdx.x * 256 + threadIdx.x;  // 32768
  const int e = tid >> 9;          // 0..63
  const int k4 = tid & 511;        // 0..511
  const float4 v = *(const float4*)(W + (size_t)e * D_MODEL + 4 * k4);
  Wt[(size_t)(4 * k4 + 0) * N_EXP + e] = v.x;
  Wt[(size_t)(4 * k4 + 1) * N_EXP + e] = v.y;
  Wt[(size_t)(4 * k4 + 2) * N_EXP + e] = v.z;
  Wt[(size_t)(4 * k4 + 3) * N_EXP + e] = v.w;
}

// ---------------- K1: split-K GEMM, no LDS, partials[slice][token][expert] --
// grid 1024 = 4 kslices x 256 tiles; 256 thr; 4x4 tile (64 tok x 64 exp).
// a-loads: 16-lane broadcast of x rows (L1). w-loads: contiguous Wt rows (L2).
__global__ __launch_bounds__(256, 4) void k1_gemm(
    const float* __restrict__ x, const float* __restrict__ Wt,
    float* __restrict__ part) {
  const int t = threadIdx.x;
  const int ks = blockIdx.x >> 8;    // k-slice 0..3
  const int grp = blockIdx.x & 255;  // tile 0..255
  const int m0 = grp * 64;
  const int kb = ks * KSLICE;

  const int tr = t >> 4;  // token base: owns tr+16i
  const int tc = t & 15;  // expert base: owns 4*tc..+3

  const float* xg = x + (size_t)(m0 + tr) * D_MODEL + kb;
  const float* wg = Wt + (size_t)kb * N_EXP + tc * 4;

  float acc[4][4] = {};

  for (int k4 = 0; k4 < KSLICE / 4; k4++) {
    float4 a0 = *(const float4*)(xg + (size_t)0 * 16 * D_MODEL + 4 * k4);
    float4 a1 = *(const float4*)(xg + (size_t)1 * 16 * D_MODEL + 4 * k4);
    float4 a2 = *(const float4*)(xg + (size_t)2 * 16 * D_MODEL + 4 * k4);
    float4 a3 = *(const float4*)(xg + (size_t)3 * 16 * D_MODEL + 4 * k4);
    float4 w0 = *(const float4*)(wg + (size_t)(4 * k4 + 0) * N_EXP);
    float4 w1 = *(const float4*)(wg + (size_t)(4 * k4 + 1) * N_EXP);
    float4 w2 = *(const float4*)(wg + (size_t)(4 * k4 + 2) * N_EXP);
    float4 w3 = *(const float4*)(wg + (size_t)(4 * k4 + 3) * N_EXP);
#define FMA_STEP(AV, WV)                         \
    acc[AV][0] = fmaf(a##AV.x, w0.x, acc[AV][0]); // placeholder
#undef FMA_STEP
    // k = 4*k4 + 0..3 ; unrolled by hand, no dynamic vector-component idx
#define ROW(i, av)                                   \
    acc[i][0] = fmaf(av, wq.x, acc[i][0]);           \
    acc[i][1] = fmaf(av, wq.y, acc[i][1]);           \
    acc[i][2] = fmaf(av, wq.z, acc[i][2]);           \
    acc[i][3] = fmaf(av, wq.w, acc[i][3]);
    {
      float4 wq = w0;
      ROW(0, a0.x) ROW(1, a1.x) ROW(2, a2.x) ROW(3, a3.x)
    }
    {
      float4 wq = w1;
      ROW(0, a0.y) ROW(1, a1.y) ROW(2, a2.y) ROW(3, a3.y)
    }
    {
      float4 wq = w2;
      ROW(0, a0.z) ROW(1, a1.z) ROW(2, a2.z) ROW(3, a3.z)
    }
    {
      float4 wq = w3;
      ROW(0, a0.w) ROW(1, a1.w) ROW(2, a2.w) ROW(3, a3.w)
    }
#undef ROW
  }

  // part[ks][n][e]: 16 lanes x float4 = 256B contiguous per i
#pragma unroll
  for (int i = 0; i < 4; i++) {
    float* pp = part + ((size_t)ks * N_TOK + m0 + tr + 16 * i) * N_EXP + tc * 4;
    *(float4*)pp = make_float4(acc[i][0], acc[i][1], acc[i][2], acc[i][3]);
  }
}

// ---------------- K2: wave-per-token softmax + top2 + z + hist --------------
__global__ __launch_bounds__(256) void k2_softmax(
    const float* __restrict__ part, float* __restrict__ rw_out,
    int2* __restrict__ top12, float2* __restrict__ wts,
    int* __restrict__ histR, float* __restrict__ zR) {
  __shared__ float zred[4];
  const int lane = threadIdx.x & 63;
  const int wid = threadIdx.x >> 6;
  const int n = blockIdx.x * 4 + wid;
  const int rep = blockIdx.x & (NREP - 1);

  float v = 0.f;
#pragma unroll
  for (int s = 0; s < KSPLIT; s++)
    v += part[((size_t)s * N_TOK + n) * N_EXP + lane];

  float zp = v * v;
#pragma unroll
  for (int off = 32; off; off >>= 1) zp += __shfl_xor(zp, off);

  float m = v;
#pragma unroll
  for (int off = 32; off; off >>= 1) m = fmaxf(m, __shfl_xor(m, off));
  float p = __expf(v - m);
  float ssum = p;
#pragma unroll
  for (int off = 32; off; off >>= 1) ssum += __shfl_xor(ssum, off);
  const float rw = p / ssum;
  rw_out[(size_t)n * N_EXP + lane] = rw;

  const unsigned long long b1 = __ballot(v == m);
  const int i1 = __builtin_ctzll(b1);
  float v2 = (lane == i1) ? -INFINITY : v;
#pragma unroll
  for (int off = 32; off; off >>= 1) v2 = fmaxf(v2, __shfl_xor(v2, off));
  const unsigned long long b2 = __ballot(v == v2) & ~(1ull << i1);
  const int i2 = __builtin_ctzll(b2);

  const float rw1 = __shfl(rw, i1);
  const float rw2 = __shfl(rw, i2);
  if (lane == 0) {
    const float denom = rw1 + rw2 + 1e-8f;
    top12[n] = make_int2(i1, i2);
    wts[n] = make_float2(rw1 / denom, rw2 / denom);
    atomicAdd(&histR[(rep * N_EXP + i1) * 16], 1);
    zred[wid] = zp;
  }
  __syncthreads();
  if (threadIdx.x == 0)
    atomicAdd(&zR[rep * 16], zred[0] + zred[1] + zred[2] + zred[3]);
}

// ---------------- K3: wave-per-token dispatch mask + counts -----------------
__global__ __launch_bounds__(256) void k3_dispatch(
    const int2* __restrict__ top12, const float2* __restrict__ wts,
    const int* __restrict__ histR, float* __restrict__ mask_out,
    float* __restrict__ cntR) {
  const int lane = threadIdx.x & 63;
  const int wid = threadIdx.x >> 6;
  const int n = blockIdx.x * 4 + wid;
  const int rep = blockIdx.x & (NREP - 1);

  const int2 ij = top12[n];
  const float2 w = wts[n];
  int h = 0;
#pragma unroll
  for (int r = 0; r < NREP; r++) h += histR[(r * N_EXP + ij.y) * 16];
  const bool allowed = h < CAPACITY;
  const float ssum = w.x + (allowed ? w.y : 0.f);
  const float inv = 1.f / (ssum + 1e-8f);
  float val = 0.f;
  if (lane == ij.x) val = w.x * inv;
  else if (allowed && lane == ij.y) val = w.y * inv;
  mask_out[(size_t)n * N_EXP + lane] = val;
  if (val != 0.f) atomicAdd(&cntR[(rep * N_EXP + lane) * 16], val);
}

// ---------------- K4: scalar loss -------------------------------------------
__global__ void k4_loss(const float* __restrict__ cntR,
                        const float* __restrict__ zR,
                        float* __restrict__ loss_out) {
  const int lane = threadIdx.x;
  float c = 0.f;
#pragma unroll
  for (int r = 0; r < NREP; r++) c += cntR[(r * N_EXP + lane) * 16];
  const float d = (c - 512.0f) * (1.0f / 16384.0f);
  float v = d * d;
#pragma unroll
  for (int off = 32; off; off >>= 1) v += __shfl_xor(v, off);
  if (lane == 0) {
    float z = 0.f;
#pragma unroll
    for (int r = 0; r < NREP; r++) z += zR[r * 16];
    const float lb = v * (1.0f / 64.0f);
    loss_out[0] = 0.001f * (z * (1.0f / (16384.0f * 64.0f))) + 0.001f * lb;
  }
}

extern "C" void kernel_launch(void* const* d_in, const int* in_sizes, int n_in,
                              void* d_out, int out_size, void* d_ws, size_t ws_size,
                              hipStream_t stream) {
  const float* x = (const float*)d_in[0];
  const float* W = (const float*)d_in[1];
  float* out = (float*)d_out;
  float* rw_out = out;
  float* mask_out = out + (size_t)N_TOK * N_EXP;
  float* loss_out = out + 2 * (size_t)N_TOK * N_EXP;

  char* ws = (char*)d_ws;
  float* part = (float*)ws;                        // 4 x 16384 x 64 x 4B = 16 MB
  float* Wt = (float*)(ws + 16777216);             // 512 KB
  int* histR = (int*)(ws + 17301504);              // 32 KB (8 reps x 64 x s16)
  float* cntR = (float*)(ws + 17301504 + 32768);   // 32 KB
  float* zR = (float*)(ws + 17301504 + 65536);     // 512 B
  int2* top12 = (int2*)(ws + 17301504 + 131072);   // 128 KB
  float2* wts = (float2*)(ws + 17301504 + 262144); // 128 KB

  hipMemsetAsync(histR, 0, 65536 + 512, stream);
  k0_transpose<<<128, 256, 0, stream>>>(W, Wt);
  k1_gemm<<<KSPLIT * 256, 256, 0, stream>>>(x, Wt, part);
  k2_softmax<<<N_TOK / 4, 256, 0, stream>>>(part, rw_out, top12, wts, histR, zR);
  k3_dispatch<<<N_TOK / 4, 256, 0, stream>>>(top12, wts, histR, mask_out, cntR);
  k4_loss<<<1, 64, 0, stream>>>(cntR, zR, loss_out);
}

// Round 7
// 276.957 us; speedup vs baseline: 1.2193x; 1.2193x over previous
//
#include <hip/hip_runtime.h>
#include <hip/hip_bf16.h>
#include <math.h>

#define N_TOK 16384
#define D_MODEL 2048
#define N_EXP 64
#define CAPACITY 640
#define KSPLIT 8
#define KSLICE (D_MODEL / KSPLIT)  // 256
#define BK 32
#define NREP 8

// ---------------- K1: split-K GEMM, partials[slice][token][expert] ----------
// grid 1024 = 8 kslices x 128 tiles; 256 thr; thread = 8 tok x 4 exp.
// x: direct global float4 (16-lane broadcast, L1). W: LDS-staged (16x reuse).
__global__ __launch_bounds__(256) void k1_gemm(
    const float* __restrict__ x, const float* __restrict__ W,
    float* __restrict__ part) {
  __shared__ float ws[BK][N_EXP];  // [k][expert], 8 KB

  const int t = threadIdx.x;
  const int ks = blockIdx.x >> 7;    // k-slice 0..7
  const int grp = blockIdx.x & 127;  // tile 0..127 (siblings share W slice)
  const int m0 = grp * 128;
  const int kb = ks * KSLICE;

  const int tr = t >> 4;  // token base: owns tr+16i, i<8
  const int tc = t & 15;  // expert base: owns 4*tc..+3
  const int we = t & 63;         // W-stage expert
  const int wc = (t >> 6) * 8;   // W-stage k chunk

  const float* xg = x + (size_t)(m0 + tr) * D_MODEL + kb;
  const float* wg = W + (size_t)we * D_MODEL + kb + wc;

  float4 wp0 = *(const float4*)wg;
  float4 wp1 = *(const float4*)(wg + 4);
  float acc[8][4] = {};

  for (int s = 0; s < KSLICE / BK; s++) {  // 8 stages
    __syncthreads();
    ws[wc + 0][we] = wp0.x; ws[wc + 1][we] = wp0.y;
    ws[wc + 2][we] = wp0.z; ws[wc + 3][we] = wp0.w;
    ws[wc + 4][we] = wp1.x; ws[wc + 5][we] = wp1.y;
    ws[wc + 6][we] = wp1.z; ws[wc + 7][we] = wp1.w;
    __syncthreads();
    if (s + 1 < KSLICE / BK) {
      wp0 = *(const float4*)(wg + (s + 1) * BK);
      wp1 = *(const float4*)(wg + (s + 1) * BK + 4);
    }
    const float* xs = xg + s * BK;
#pragma unroll 2
    for (int k4 = 0; k4 < BK / 4; k4++) {
      float4 a[8];
#pragma unroll
      for (int i = 0; i < 8; i++)
        a[i] = *(const float4*)(xs + (size_t)(16 * i) * D_MODEL + 4 * k4);
      const float4 w0 = *(const float4*)&ws[4 * k4 + 0][tc * 4];
      const float4 w1 = *(const float4*)&ws[4 * k4 + 1][tc * 4];
      const float4 w2 = *(const float4*)&ws[4 * k4 + 2][tc * 4];
      const float4 w3 = *(const float4*)&ws[4 * k4 + 3][tc * 4];
#pragma unroll
      for (int i = 0; i < 8; i++) {
        acc[i][0] = fmaf(a[i].x, w0.x, acc[i][0]);
        acc[i][1] = fmaf(a[i].x, w0.y, acc[i][1]);
        acc[i][2] = fmaf(a[i].x, w0.z, acc[i][2]);
        acc[i][3] = fmaf(a[i].x, w0.w, acc[i][3]);
        acc[i][0] = fmaf(a[i].y, w1.x, acc[i][0]);
        acc[i][1] = fmaf(a[i].y, w1.y, acc[i][1]);
        acc[i][2] = fmaf(a[i].y, w1.z, acc[i][2]);
        acc[i][3] = fmaf(a[i].y, w1.w, acc[i][3]);
        acc[i][0] = fmaf(a[i].z, w2.x, acc[i][0]);
        acc[i][1] = fmaf(a[i].z, w2.y, acc[i][1]);
        acc[i][2] = fmaf(a[i].z, w2.z, acc[i][2]);
        acc[i][3] = fmaf(a[i].z, w2.w, acc[i][3]);
        acc[i][0] = fmaf(a[i].w, w3.x, acc[i][0]);
        acc[i][1] = fmaf(a[i].w, w3.y, acc[i][1]);
        acc[i][2] = fmaf(a[i].w, w3.z, acc[i][2]);
        acc[i][3] = fmaf(a[i].w, w3.w, acc[i][3]);
      }
    }
  }
  // part[ks][n][e]: 16 lanes x float4 = 256 B contiguous per i
#pragma unroll
  for (int i = 0; i < 8; i++) {
    float* pp = part + ((size_t)ks * N_TOK + m0 + tr + 16 * i) * N_EXP + tc * 4;
    *(float4*)pp = make_float4(acc[i][0], acc[i][1], acc[i][2], acc[i][3]);
  }
}

// ---------------- K2: wave-per-token softmax + top2 + z + hist --------------
__global__ __launch_bounds__(256) void k2_softmax(
    const float* __restrict__ part, float* __restrict__ rw_out,
    int2* __restrict__ top12, float2* __restrict__ wts,
    int* __restrict__ histR, float* __restrict__ zR) {
  __shared__ float zred[4];
  const int lane = threadIdx.x & 63;
  const int wid = threadIdx.x >> 6;
  const int n = blockIdx.x * 4 + wid;
  const int rep = blockIdx.x & (NREP - 1);

  float v = 0.f;
#pragma unroll
  for (int s = 0; s < KSPLIT; s++)
    v += part[((size_t)s * N_TOK + n) * N_EXP + lane];

  float zp = v * v;
#pragma unroll
  for (int off = 32; off; off >>= 1) zp += __shfl_xor(zp, off);

  float m = v;
#pragma unroll
  for (int off = 32; off; off >>= 1) m = fmaxf(m, __shfl_xor(m, off));
  float p = __expf(v - m);
  float ssum = p;
#pragma unroll
  for (int off = 32; off; off >>= 1) ssum += __shfl_xor(ssum, off);
  const float rw = p / ssum;
  rw_out[(size_t)n * N_EXP + lane] = rw;

  const unsigned long long b1 = __ballot(v == m);
  const int i1 = __builtin_ctzll(b1);
  float v2 = (lane == i1) ? -INFINITY : v;
#pragma unroll
  for (int off = 32; off; off >>= 1) v2 = fmaxf(v2, __shfl_xor(v2, off));
  const unsigned long long b2 = __ballot(v == v2) & ~(1ull << i1);
  const int i2 = __builtin_ctzll(b2);

  const float rw1 = __shfl(rw, i1);
  const float rw2 = __shfl(rw, i2);
  if (lane == 0) {
    const float denom = rw1 + rw2 + 1e-8f;
    top12[n] = make_int2(i1, i2);
    wts[n] = make_float2(rw1 / denom, rw2 / denom);
    atomicAdd(&histR[(rep * N_EXP + i1) * 16], 1);
    zred[wid] = zp;
  }
  __syncthreads();
  if (threadIdx.x == 0)
    atomicAdd(&zR[rep * 16], zred[0] + zred[1] + zred[2] + zred[3]);
}

// ---------------- K3: wave-per-token dispatch mask + counts -----------------
__global__ __launch_bounds__(256) void k3_dispatch(
    const int2* __restrict__ top12, const float2* __restrict__ wts,
    const int* __restrict__ histR, float* __restrict__ mask_out,
    float* __restrict__ cntR) {
  const int lane = threadIdx.x & 63;
  const int wid = threadIdx.x >> 6;
  const int n = blockIdx.x * 4 + wid;
  const int rep = blockIdx.x & (NREP - 1);

  const int2 ij = top12[n];
  const float2 w = wts[n];
  int h = 0;
#pragma unroll
  for (int r = 0; r < NREP; r++) h += histR[(r * N_EXP + ij.y) * 16];
  const bool allowed = h < CAPACITY;
  const float ssum = w.x + (allowed ? w.y : 0.f);
  const float inv = 1.f / (ssum + 1e-8f);
  float val = 0.f;
  if (lane == ij.x) val = w.x * inv;
  else if (allowed && lane == ij.y) val = w.y * inv;
  mask_out[(size_t)n * N_EXP + lane] = val;
  if (val != 0.f) atomicAdd(&cntR[(rep * N_EXP + lane) * 16], val);
}

// ---------------- K4: scalar loss -------------------------------------------
__global__ void k4_loss(const float* __restrict__ cntR,
                        const float* __restrict__ zR,
                        float* __restrict__ loss_out) {
  const int lane = threadIdx.x;
  float c = 0.f;
#pragma unroll
  for (int r = 0; r < NREP; r++) c += cntR[(r * N_EXP + lane) * 16];
  const float d = (c - 512.0f) * (1.0f / 16384.0f);
  float v = d * d;
#pragma unroll
  for (int off = 32; off; off >>= 1) v += __shfl_xor(v, off);
  if (lane == 0) {
    float z = 0.f;
#pragma unroll
    for (int r = 0; r < NREP; r++) z += zR[r * 16];
    const float lb = v * (1.0f / 64.0f);
    loss_out[0] = 0.001f * (z * (1.0f / (16384.0f * 64.0f))) + 0.001f * lb;
  }
}

extern "C" void kernel_launch(void* const* d_in, const int* in_sizes, int n_in,
                              void* d_out, int out_size, void* d_ws, size_t ws_size,
                              hipStream_t stream) {
  const float* x = (const float*)d_in[0];
  const float* W = (const float*)d_in[1];
  float* out = (float*)d_out;
  float* rw_out = out;
  float* mask_out = out + (size_t)N_TOK * N_EXP;
  float* loss_out = out + 2 * (size_t)N_TOK * N_EXP;

  char* ws = (char*)d_ws;
  float* part = (float*)ws;                        // 8 x 16384 x 64 x 4B = 32 MB
  int* histR = (int*)(ws + 33554432);              // 32 KB (8 reps x 64 x s16)
  float* cntR = (float*)(ws + 33554432 + 32768);   // 32 KB
  float* zR = (float*)(ws + 33554432 + 65536);     // 512 B
  int2* top12 = (int2*)(ws + 33554432 + 131072);   // 128 KB
  float2* wts = (float2*)(ws + 33554432 + 262144); // 128 KB

  hipMemsetAsync(histR, 0, 65536 + 512, stream);
  k1_gemm<<<KSPLIT * 128, 256, 0, stream>>>(x, W, part);
  k2_softmax<<<N_TOK / 4, 256, 0, stream>>>(part, rw_out, top12, wts, histR, zR);
  k3_dispatch<<<N_TOK / 4, 256, 0, stream>>>(top12, wts, histR, mask_out, cntR);
  k4_loss<<<1, 64, 0, stream>>>(cntR, zR, loss_out);
}